// Round 13
// baseline (418.089 us; speedup 1.0000x reference)
//
#include <hip/hip_runtime.h>
#include <hip/hip_fp16.h>

#define IN_DIM 128
#define HID    256
#define LAT    64

typedef __attribute__((ext_vector_type(8))) short bf16x8;
typedef __attribute__((ext_vector_type(4))) float f32x4;

// ---------------------------------------------------------------------------
// bf16 split helpers (round-to-nearest-even)
// ---------------------------------------------------------------------------
__device__ __forceinline__ short f2bf(float f) {
    union { float f; unsigned u; } v; v.f = f;
    unsigned r = v.u + 0x7fffu + ((v.u >> 16) & 1u);
    return (short)(r >> 16);
}
__device__ __forceinline__ float bf2f(short s) {
    union { unsigned u; float f; } v; v.u = ((unsigned)(unsigned short)s) << 16;
    return v.f;
}

__device__ __forceinline__ void storeP(__half* p, float v) { *p = __float2half(v); }
__device__ __forceinline__ void storeP(float*  p, float v) { *p = v; }

// ---------------------------------------------------------------------------
// Preprocessing: packed u64 atomic (count | Q20 weight-sum) -> rank; CSR fill
// without atomics. CSR entries are int2 {row, norm-bits}.
// ---------------------------------------------------------------------------

#define FIXSCALE 1048576.0f   // 2^20

__global__ void k_init(unsigned long long* __restrict__ packed, int n) {
    int i = blockIdx.x * 256 + threadIdx.x;
    if (i < n) packed[i] = (unsigned long long)(1u << 20);   // self-loop, count 0
}

__global__ void k_edge_acc(const int* __restrict__ ei, const float* __restrict__ ew,
                           unsigned long long* __restrict__ packed,
                           int* __restrict__ rank, int E) {
    int e = blockIdx.x * 256 + threadIdx.x;
    if (e < E) {
        int c = ei[E + e];
        unsigned fx = (unsigned)lrintf(ew[e] * FIXSCALE);
        unsigned long long old =
            atomicAdd(&packed[c], ((unsigned long long)1 << 40) | (unsigned long long)fx);
        rank[e] = (int)(old >> 40);
    }
}

__global__ void k_derive(const unsigned long long* __restrict__ packed,
                         float* __restrict__ dinv, int* __restrict__ counts, int n) {
    int i = blockIdx.x * 256 + threadIdx.x;
    if (i < n) {
        unsigned long long p = packed[i];
        float deg = (float)(p & (((unsigned long long)1 << 40) - 1)) * (1.0f / FIXSCALE);
        dinv[i]   = rsqrtf(deg);           // deg >= 1 (self loop)
        counts[i] = (int)(p >> 40);
    }
}

// --- coalesced 3-phase exclusive scan (n <= 64*1024) ---
__global__ __launch_bounds__(1024) void k_blocksum(const int* __restrict__ counts,
                                                   int* __restrict__ bsum, int n) {
    __shared__ int ws[16];
    const int t = threadIdx.x, lane = t & 63, wv = t >> 6;
    int i = blockIdx.x * 1024 + t;
    int v = (i < n) ? counts[i] : 0;
    #pragma unroll
    for (int d = 1; d < 64; d <<= 1) v += __shfl_xor(v, d);
    if (lane == 0) ws[wv] = v;
    __syncthreads();
    if (wv == 0 && lane < 16) {
        int x = ws[lane];
        #pragma unroll
        for (int d = 1; d < 16; d <<= 1) x += __shfl_xor(x, d, 16);
        if (lane == 0) bsum[blockIdx.x] = x;
    }
}

__global__ void k_scan_bsums(int* __restrict__ bsum, int nb,
                             int* __restrict__ offsets, int n) {
    int lane = threadIdx.x;          // 64 threads
    int v = (lane < nb) ? bsum[lane] : 0;
    #pragma unroll
    for (int d = 1; d < 64; d <<= 1) {
        int u = __shfl_up(v, d);
        if (lane >= d) v += u;
    }
    if (lane < nb) bsum[lane] = v;   // inclusive
    if (lane == nb - 1) offsets[n] = v;
}

__global__ __launch_bounds__(1024) void k_scan_apply(const int* __restrict__ counts,
                                                     const int* __restrict__ bsum,
                                                     int* __restrict__ offsets, int n) {
    __shared__ int ws[16];
    const int t = threadIdx.x, lane = t & 63, wv = t >> 6;
    int i = blockIdx.x * 1024 + t;
    int v = (i < n) ? counts[i] : 0;
    int s = v;
    #pragma unroll
    for (int d = 1; d < 64; d <<= 1) {
        int u = __shfl_up(s, d);
        if (lane >= d) s += u;
    }
    if (lane == 63) ws[wv] = s;
    __syncthreads();
    if (wv == 0 && lane < 16) {
        int x = ws[lane];
        #pragma unroll
        for (int d = 1; d < 16; d <<= 1) {
            int u = __shfl_up(x, d, 16);
            if (lane >= d) x += u;
        }
        ws[lane] = x;
    }
    __syncthreads();
    int base = (blockIdx.x ? bsum[blockIdx.x - 1] : 0) + (wv ? ws[wv - 1] : 0);
    if (i < n) offsets[i] = base + s - v;
}

// atomic-free CSR fill: pos = offsets[col] + rank[e]; int2 {row, norm}
__global__ void k_fill(const int* __restrict__ ei, const float* __restrict__ ew,
                       const float* __restrict__ dinv, const int* __restrict__ offsets,
                       const int* __restrict__ rank,
                       int2* __restrict__ csr, int E) {
    int e = blockIdx.x * 256 + threadIdx.x;
    if (e < E) {
        int r = ei[e];
        int c = ei[E + e];
        int pos = offsets[c] + rank[e];
        float nm = dinv[r] * ew[e] * dinv[c];
        csr[pos] = make_int2(r, __float_as_int(nm));
    }
}

// fp32 -> f16 cast, 8 elems/thread (total % 8 == 0)
__global__ void k_cast(const float* __restrict__ x, __half* __restrict__ xh, int total) {
    int idx = (blockIdx.x * 256 + threadIdx.x) * 8;
    if (idx < total) {
        float4 a = *(const float4*)&x[idx];
        float4 b = *(const float4*)&x[idx + 4];
        short4 s0 = make_short4(__half_as_short(__float2half(a.x)), __half_as_short(__float2half(a.y)),
                                __half_as_short(__float2half(a.z)), __half_as_short(__float2half(a.w)));
        short4 s1 = make_short4(__half_as_short(__float2half(b.x)), __half_as_short(__float2half(b.y)),
                                __half_as_short(__float2half(b.z)), __half_as_short(__float2half(b.w)));
        *(short4*)&xh[idx]     = s0;
        *(short4*)&xh[idx + 4] = s1;
    }
}

// all 4 weight matrices -> pre-split, TRANSPOSED [F][K] bf16 hi/lo planes.
// Fragment reads in the GEMM become 16B contiguous global loads (L2-resident).
__global__ void k_splitW_all(
    const float* __restrict__ W1, short* __restrict__ H1, short* __restrict__ G1, int K1, int F1,
    const float* __restrict__ W2, short* __restrict__ H2, short* __restrict__ G2, int K2, int F2,
    const float* __restrict__ W3, short* __restrict__ H3, short* __restrict__ G3, int K3, int F3,
    const float* __restrict__ W4, short* __restrict__ H4, short* __restrict__ G4, int K4, int F4) {
    int idx = blockIdx.x * 256 + threadIdx.x;
    const int n1 = K1 * F1, n2 = K2 * F2, n3 = K3 * F3, n4 = K4 * F4;
    const float* W; short* H; short* G; int K, F;
    if (idx < n1)                          { W = W1; H = H1; G = G1; K = K1; F = F1; }
    else if (idx < n1 + n2)                { idx -= n1;           W = W2; H = H2; G = G2; K = K2; F = F2; }
    else if (idx < n1 + n2 + n3)           { idx -= n1 + n2;      W = W3; H = H3; G = G3; K = K3; F = F3; }
    else if (idx < n1 + n2 + n3 + n4)      { idx -= n1 + n2 + n3; W = W4; H = H4; G = G4; K = K4; F = F4; }
    else return;
    int k = idx / F, f = idx % F;
    float w = W[idx];
    short h = f2bf(w);
    short l = f2bf(w - bf2f(h));
    H[(size_t)f * K + k] = h;
    G[(size_t)f * K + k] = l;
}

// ---------------------------------------------------------------------------
// MFMA GEMM, bf16 Markidis split: P[M,F] = A_f32[M,K] @ W[K,F] (+b,relu).
// A staged in LDS (coalesced HBM reads); W fragments read DIRECTLY from the
// pre-split transposed [F][K] hi/lo planes (L2-resident, 16B/lane loads) —
// halves LDS (20.5KB -> ~6 blocks/CU) and kills the 8-way W-staging bank
// conflicts seen in r12 (SQ_LDS_BANK_CONFLICT 1.2M).
// BM=128, BK=32, BN template (64 or 128). 256 threads = 4 waves in 2x2 grid.
// EPI=true fuses o = relu(o + bias[col]). K % 32 == 0.
// ---------------------------------------------------------------------------
template <int BN, typename PT, bool EPI>
__global__ __launch_bounds__(256) void gemm_mfma(const float* __restrict__ A,
                                                 const short* __restrict__ Wth,
                                                 const short* __restrict__ Wtl,
                                                 const float* __restrict__ bias,
                                                 PT* __restrict__ P,
                                                 int M, int K, int F) {
    constexpr int WC = BN / 32;          // col fragments per wave
    __shared__ alignas(16) short Ahi[128][40];
    __shared__ alignas(16) short Alo[128][40];

    const int bm  = blockIdx.x * 128;
    const int bn  = blockIdx.y * BN;
    const int tid = threadIdx.x;
    const int wv  = tid >> 6;
    const int wy  = wv >> 1;             // 0..1 : row half
    const int wx  = wv & 1;              // 0..1 : col half
    const int lane = tid & 63;
    const int frow = lane & 15;
    const int fk   = (lane >> 4) * 8;

    // per-wave W column base offsets (lane-dependent via frow)
    size_t wbase[WC];
    #pragma unroll
    for (int wc = 0; wc < WC; ++wc)
        wbase[wc] = (size_t)(bn + wx * (BN / 2) + wc * 16 + frow) * K + fk;

    f32x4 acc[4][WC];
    #pragma unroll
    for (int i = 0; i < 4; ++i)
        #pragma unroll
        for (int j = 0; j < WC; ++j)
            acc[i][j] = (f32x4){0.f, 0.f, 0.f, 0.f};

    for (int k0 = 0; k0 < K; k0 += 32) {
        if (k0) __syncthreads();
        // --- stage A: 128 rows x 32 k, float4 global loads, split to hi/lo ---
        #pragma unroll
        for (int it = 0; it < 4; ++it) {
            int l   = tid + it * 256;
            int row = l >> 3;
            int k4  = l & 7;
            int gr  = bm + row;
            float4 v = make_float4(0.f, 0.f, 0.f, 0.f);
            if (gr < M) v = *(const float4*)&A[(size_t)gr * K + k0 + k4 * 4];
            float vv[4] = {v.x, v.y, v.z, v.w};
            short h[4], lo[4];
            #pragma unroll
            for (int j = 0; j < 4; ++j) {
                h[j]  = f2bf(vv[j]);
                lo[j] = f2bf(vv[j] - bf2f(h[j]));
            }
            *(short4*)&Ahi[row][k4 * 4] = make_short4(h[0], h[1], h[2], h[3]);
            *(short4*)&Alo[row][k4 * 4] = make_short4(lo[0], lo[1], lo[2], lo[3]);
        }
        // --- W fragments: direct 16B global loads from transposed planes ---
        bf16x8 wh[WC], wl[WC];
        #pragma unroll
        for (int wc = 0; wc < WC; ++wc) {
            wh[wc] = *(const bf16x8*)&Wth[wbase[wc] + k0];
            wl[wc] = *(const bf16x8*)&Wtl[wbase[wc] + k0];
        }
        __syncthreads();
        bf16x8 ah[4], al[4];
        #pragma unroll
        for (int ar = 0; ar < 4; ++ar) {
            ah[ar] = *(const bf16x8*)&Ahi[wy * 64 + ar * 16 + frow][fk];
            al[ar] = *(const bf16x8*)&Alo[wy * 64 + ar * 16 + frow][fk];
        }
        #pragma unroll
        for (int ar = 0; ar < 4; ++ar)
            #pragma unroll
            for (int wc = 0; wc < WC; ++wc) {
                acc[ar][wc] = __builtin_amdgcn_mfma_f32_16x16x32_bf16(ah[ar], wh[wc], acc[ar][wc], 0, 0, 0);
                acc[ar][wc] = __builtin_amdgcn_mfma_f32_16x16x32_bf16(ah[ar], wl[wc], acc[ar][wc], 0, 0, 0);
                acc[ar][wc] = __builtin_amdgcn_mfma_f32_16x16x32_bf16(al[ar], wh[wc], acc[ar][wc], 0, 0, 0);
            }
    }
    #pragma unroll
    for (int ar = 0; ar < 4; ++ar)
        #pragma unroll
        for (int r = 0; r < 4; ++r) {
            int row = bm + wy * 64 + ar * 16 + (lane >> 4) * 4 + r;
            if (row >= M) continue;
            #pragma unroll
            for (int wc = 0; wc < WC; ++wc) {
                int col = bn + wx * (BN / 2) + wc * 16 + (lane & 15);
                float o = acc[ar][wc][r];
                if (EPI) o = fmaxf(o + bias[col], 0.f);
                storeP(&P[(size_t)row * F + col], o);
            }
        }
}

// ---------------------------------------------------------------------------
// Aggregation: out[c] = sn*self[c] + sum_e norm_e * pre[row_e] (+ bias)
// Neighbor gathers from TN* pre (f16 for traffic), self term from TS* self.
// One wave per node, lane-vectorized (F = VEC*64); 8-edge unroll for MLP.
// ---------------------------------------------------------------------------

template <int VEC>
__device__ __forceinline__ void pload(float* d, const __half* s) {
    if constexpr (VEC == 4) {
        union { short4 s4; __half h[4]; } u;
        u.s4 = *(const short4*)s;
        #pragma unroll
        for (int j = 0; j < 4; ++j) d[j] = __half2float(u.h[j]);
    } else if constexpr (VEC == 2) {
        union { short2 s2; __half h[2]; } u;
        u.s2 = *(const short2*)s;
        d[0] = __half2float(u.h[0]); d[1] = __half2float(u.h[1]);
    } else {
        d[0] = __half2float(*s);
    }
}
template <int VEC>
__device__ __forceinline__ void pload(float* d, const float* s) {
    if constexpr (VEC == 4) { float4 v = *(const float4*)s; d[0]=v.x; d[1]=v.y; d[2]=v.z; d[3]=v.w; }
    else if constexpr (VEC == 2) { float2 v = *(const float2*)s; d[0]=v.x; d[1]=v.y; }
    else { d[0] = *s; }
}
template <int VEC>
__device__ __forceinline__ void pstore(__half* d, const float* s) {
    if constexpr (VEC == 4) {
        *(short4*)d = make_short4(__half_as_short(__float2half(s[0])), __half_as_short(__float2half(s[1])),
                                  __half_as_short(__float2half(s[2])), __half_as_short(__float2half(s[3])));
    } else if constexpr (VEC == 2) {
        *(short2*)d = make_short2(__half_as_short(__float2half(s[0])), __half_as_short(__float2half(s[1])));
    } else {
        *d = __float2half(s[0]);
    }
}
template <int VEC>
__device__ __forceinline__ void pstore(float* d, const float* s) {
    if constexpr (VEC == 4) { *(float4*)d = make_float4(s[0], s[1], s[2], s[3]); }
    else if constexpr (VEC == 2) { *(float2*)d = make_float2(s[0], s[1]); }
    else { *d = s[0]; }
}

template <int VEC, bool HASB, typename TN, typename TS, typename TOUT>
__global__ __launch_bounds__(256) void agg_kernel(
    const TN* __restrict__ pre, const TS* __restrict__ self,
    const float* __restrict__ bias,
    const int* __restrict__ offsets, const int2* __restrict__ csr,
    const float* __restrict__ dinv, TOUT* __restrict__ out, int n) {
    constexpr int F = VEC * 64;
    const int wave = threadIdx.x >> 6;
    const int lane = threadIdx.x & 63;
    const int c = blockIdx.x * 4 + wave;
    if (c >= n) return;
    const float di = dinv[c];
    const float sn = di * di;
    float acc[VEC];
    pload<VEC>(acc, self + (size_t)c * F + lane * VEC);
    #pragma unroll
    for (int v = 0; v < VEC; ++v) acc[v] *= sn;
    const int beg = offsets[c], end = offsets[c + 1];
    int j = beg;
    // 8-edge unroll: 8 independent gathers in flight per iteration
    for (; j + 7 < end; j += 8) {
        int2 e[8];
        #pragma unroll
        for (int q = 0; q < 8; ++q) e[q] = csr[j + q];
        float t[8][VEC];
        #pragma unroll
        for (int q = 0; q < 8; ++q)
            pload<VEC>(t[q], pre + (size_t)e[q].x * F + lane * VEC);
        #pragma unroll
        for (int q = 0; q < 8; ++q)
            #pragma unroll
            for (int v = 0; v < VEC; ++v)
                acc[v] = fmaf(__int_as_float(e[q].y), t[q][v], acc[v]);
    }
    for (; j + 3 < end; j += 4) {
        int2 e[4];
        #pragma unroll
        for (int q = 0; q < 4; ++q) e[q] = csr[j + q];
        float t[4][VEC];
        #pragma unroll
        for (int q = 0; q < 4; ++q)
            pload<VEC>(t[q], pre + (size_t)e[q].x * F + lane * VEC);
        #pragma unroll
        for (int q = 0; q < 4; ++q)
            #pragma unroll
            for (int v = 0; v < VEC; ++v)
                acc[v] = fmaf(__int_as_float(e[q].y), t[q][v], acc[v]);
    }
    for (; j < end; ++j) {
        int2 e0 = csr[j];
        float t0[VEC];
        pload<VEC>(t0, pre + (size_t)e0.x * F + lane * VEC);
        #pragma unroll
        for (int v = 0; v < VEC; ++v) acc[v] = fmaf(__int_as_float(e0.y), t0[v], acc[v]);
    }
    if (HASB) {
        float bv[VEC];
        pload<VEC>(bv, bias + lane * VEC);
        #pragma unroll
        for (int v = 0; v < VEC; ++v) acc[v] += bv[v];
    }
    pstore<VEC>(out + (size_t)c * F + lane * VEC, acc);
}

// ---------------------------------------------------------------------------

extern "C" void kernel_launch(void* const* d_in, const int* in_sizes, int n_in,
                              void* d_out, int out_size, void* d_ws, size_t ws_size,
                              hipStream_t stream) {
    const float* x  = (const float*)d_in[0];
    const int*   ei = (const int*)  d_in[1];   // [2,E] int32
    const float* ew = (const float*)d_in[2];
    const float* W1 = (const float*)d_in[3];
    const float* b1 = (const float*)d_in[4];
    const float* W2 = (const float*)d_in[5];
    const float* b2 = (const float*)d_in[6];
    const float* W3 = (const float*)d_in[7];
    const float* b3 = (const float*)d_in[8];
    const float* W4 = (const float*)d_in[9];
    const float* b4 = (const float*)d_in[10];

    const int N = in_sizes[0] / IN_DIM;
    const int E = in_sizes[2];

    char* p = (char*)d_ws;
    auto alloc = [&](size_t bytes) -> void* {
        void* r = (void*)p;
        p += (bytes + 255) & ~(size_t)255;
        return r;
    };
    unsigned long long* packed = (unsigned long long*)alloc((size_t)N * 8);
    float*  dinv     = (float*)alloc((size_t)N * 4);
    int*    counts   = (int*)  alloc((size_t)N * 4);
    int*    offsets  = (int*)  alloc((size_t)(N + 1) * 4);
    int*    bsum     = (int*)  alloc((size_t)64 * 4);
    int*    rank     = (int*)  alloc((size_t)E * 4);
    int2*   csr      = (int2*) alloc((size_t)E * 8);
    short*  Wh1      = (short*)alloc((size_t)IN_DIM * HID * 2);
    short*  Wl1      = (short*)alloc((size_t)IN_DIM * HID * 2);
    short*  Wh2      = (short*)alloc((size_t)HID * LAT * 2);
    short*  Wl2      = (short*)alloc((size_t)HID * LAT * 2);
    short*  Wh3      = (short*)alloc((size_t)LAT * HID * 2);
    short*  Wl3      = (short*)alloc((size_t)LAT * HID * 2);
    short*  Wh4      = (short*)alloc((size_t)HID * IN_DIM * 2);
    short*  Wl4      = (short*)alloc((size_t)HID * IN_DIM * 2);
    __half* xh       = (__half*)alloc((size_t)N * IN_DIM * 2);  // reused: za (L3), P4h (L4)
    float*  ha       = (float*) alloc((size_t)N * IN_DIM * 4);  // reused: P4 (L4)
    float*  h        = (float*) alloc((size_t)N * HID * 4);     // h1 / h3 (time-shared)
    __half* P2       = (__half*)alloc((size_t)N * LAT * 2);
    __half* zh       = (__half*)alloc((size_t)N * LAT * 2);
    float*  za       = (float*)xh;    // N*64*4 == N*128*2 bytes; xh dead after L1 agg
    float*  P4       = ha;            // ha dead after L1 GEMM
    __half* P4h      = xh;            // za dead after L3 GEMM

    const int gN  = (N + 255) / 256;
    const int gE  = (E + 255) / 256;
    const int nbS = (N + 1023) / 1024;   // scan blocks (49 for N=50000; must be <=64)
    const int nbM = (N + 127) / 128;
    const int nodeBlocks = (N + 3) / 4;
    const int castBlocks = (N * IN_DIM / 8 + 255) / 256;
    const int nW = IN_DIM * HID + HID * LAT + LAT * HID + HID * IN_DIM;

    // --- normalization + CSR build (1 atomic per edge total) ---
    k_init      <<<gN, 256, 0, stream>>>(packed, N);
    k_edge_acc  <<<gE, 256, 0, stream>>>(ei, ew, packed, rank, E);
    k_derive    <<<gN, 256, 0, stream>>>(packed, dinv, counts, N);
    k_blocksum  <<<nbS, 1024, 0, stream>>>(counts, bsum, N);
    k_scan_bsums<<<1, 64, 0, stream>>>(bsum, nbS, offsets, N);
    k_scan_apply<<<nbS, 1024, 0, stream>>>(counts, bsum, offsets, N);
    k_fill      <<<gE, 256, 0, stream>>>(ei, ew, dinv, offsets, rank, csr, E);
    k_cast      <<<castBlocks, 256, 0, stream>>>(x, xh, N * IN_DIM);
    k_splitW_all<<<(nW + 255) / 256, 256, 0, stream>>>(
        W1, Wh1, Wl1, IN_DIM, HID,  W2, Wh2, Wl2, HID, LAT,
        W3, Wh3, Wl3, LAT, HID,     W4, Wh4, Wl4, HID, IN_DIM);

    // --- layer 1 (agg-first): ha = A_hat @ f16(x); h1 = relu(ha @ W1 + b1) ---
    agg_kernel<2, false, __half, __half, float><<<nodeBlocks, 256, 0, stream>>>(xh, xh, nullptr, offsets, csr, dinv, ha, N);
    gemm_mfma<128, float, true><<<dim3(nbM, HID / 128), 256, 0, stream>>>(ha, Wh1, Wl1, b1, h, N, IN_DIM, HID);

    // --- layer 2 (gemm-first): P2 = h1 @ W2; z = A_hat @ P2 + b2 (stored f16) ---
    gemm_mfma<64, __half, false><<<dim3(nbM, LAT / 64), 256, 0, stream>>>(h, Wh2, Wl2, nullptr, P2, N, HID, LAT);
    agg_kernel<1, true, __half, __half, __half><<<nodeBlocks, 256, 0, stream>>>(P2, P2, b2, offsets, csr, dinv, zh, N);

    // --- layer 3 (agg-first): za = A_hat @ zh; h3 = relu(za @ W3 + b3) ---
    agg_kernel<1, false, __half, __half, float><<<nodeBlocks, 256, 0, stream>>>(zh, zh, nullptr, offsets, csr, dinv, za, N);
    gemm_mfma<128, float, true><<<dim3(nbM, HID / 128), 256, 0, stream>>>(za, Wh3, Wl3, b3, h, N, LAT, HID);

    // --- layer 4 (gemm-first): P4 = h3 @ W4 (fp32) + f16 shadow for gathers;
    //     out = sn*P4_f32[self] + sum norm*P4h_f16[nbr] + b4 ---
    gemm_mfma<128, float, false><<<dim3(nbM, IN_DIM / 128), 256, 0, stream>>>(h, Wh4, Wl4, nullptr, P4, N, HID, IN_DIM);
    k_cast<<<castBlocks, 256, 0, stream>>>(P4, P4h, N * IN_DIM);
    agg_kernel<2, true, __half, float, float><<<nodeBlocks, 256, 0, stream>>>(P4h, P4, b4, offsets, csr, dinv, (float*)d_out, N);
}